// Round 5
// baseline (32226.993 us; speedup 1.0000x reference)
//
#include <hip/hip_runtime.h>
#include <math.h>

#define BB 32
#define TT 500
#define HH 640
#define VV 1024
#define NWG 256

typedef float f32x4 __attribute__((ext_vector_type(4)));
typedef float f32x2 __attribute__((ext_vector_type(2)));
typedef unsigned int u32x2 __attribute__((ext_vector_type(2)));

// ws layout (float offsets)
//  ENC    : 0           (16000*640 = 10,240,000)
//  EW     : 10,240,000  (1024*2560 =  2,621,440)
//  h      : 12,861,440  (32*640)
//  c      : 12,881,920  (32*640)
//  Tt     : 12,902,400  (32*640)
//  G      : 12,922,880  (32*2560 -> ends 13,004,800)
//  pmax   : 13,004,800  (32*256 u64 = 16,384 floats)
//  psum   : 13,021,184  (32*256 = 8,192 floats)
//  scores : 13,029,376  (64)
//  arrive : 13,029,440  (256 slots x 32 u32)
//  release: 13,037,632  (256 slots x 32 u32)

__device__ __forceinline__ float sigf(float x) { return 1.0f / (1.0f + expf(-x)); }

__device__ __forceinline__ unsigned int fkey(float x) {
    unsigned int u = __float_as_uint(x);
    return (u & 0x80000000u) ? ~u : (u | 0x80000000u);
}

__device__ __forceinline__ unsigned long long shflxor_u64(unsigned long long v, int m) {
    unsigned int lo = (unsigned int)v, hi = (unsigned int)(v >> 32);
    lo = (unsigned int)__shfl_xor((int)lo, m);
    hi = (unsigned int)__shfl_xor((int)hi, m);
    return ((unsigned long long)hi << 32) | lo;
}

// ---- coherent (LLC-level) stores: bypass L1/L2 so no fences are needed ----
__device__ __forceinline__ void stg1_sc(float* p, float v) {
    asm volatile("global_store_dword %0, %1, off sc0 sc1" :: "v"(p), "v"(v) : "memory");
}
__device__ __forceinline__ void stg2_sc(float* p, f32x2 v) {
    asm volatile("global_store_dwordx2 %0, %1, off sc0 sc1" :: "v"(p), "v"(v) : "memory");
}
__device__ __forceinline__ void stg4_sc(float* p, f32x4 v) {
    asm volatile("global_store_dwordx4 %0, %1, off sc0 sc1" :: "v"(p), "v"(v) : "memory");
}
__device__ __forceinline__ void stg2u_sc(unsigned long long* p, unsigned long long v) {
    u32x2 uv; uv.x = (unsigned int)v; uv.y = (unsigned int)(v >> 32);
    asm volatile("global_store_dwordx2 %0, %1, off sc0 sc1" :: "v"(p), "v"(uv) : "memory");
}

// Stage one 80-float contiguous slice (coherent global) into LDS.
// Single asm block: 20 loads + one waitcnt => results valid at block end.
__device__ __forceinline__ void stage_rows(const float* src, float* dst) {
    f32x4 t0,t1,t2,t3,t4,t5,t6,t7,t8,t9,t10,t11,t12,t13,t14,t15,t16,t17,t18,t19;
    asm volatile(
        "global_load_dwordx4 %0,  %20, off sc0 sc1\n\t"
        "global_load_dwordx4 %1,  %20, off offset:16 sc0 sc1\n\t"
        "global_load_dwordx4 %2,  %20, off offset:32 sc0 sc1\n\t"
        "global_load_dwordx4 %3,  %20, off offset:48 sc0 sc1\n\t"
        "global_load_dwordx4 %4,  %20, off offset:64 sc0 sc1\n\t"
        "global_load_dwordx4 %5,  %20, off offset:80 sc0 sc1\n\t"
        "global_load_dwordx4 %6,  %20, off offset:96 sc0 sc1\n\t"
        "global_load_dwordx4 %7,  %20, off offset:112 sc0 sc1\n\t"
        "global_load_dwordx4 %8,  %20, off offset:128 sc0 sc1\n\t"
        "global_load_dwordx4 %9,  %20, off offset:144 sc0 sc1\n\t"
        "global_load_dwordx4 %10, %20, off offset:160 sc0 sc1\n\t"
        "global_load_dwordx4 %11, %20, off offset:176 sc0 sc1\n\t"
        "global_load_dwordx4 %12, %20, off offset:192 sc0 sc1\n\t"
        "global_load_dwordx4 %13, %20, off offset:208 sc0 sc1\n\t"
        "global_load_dwordx4 %14, %20, off offset:224 sc0 sc1\n\t"
        "global_load_dwordx4 %15, %20, off offset:240 sc0 sc1\n\t"
        "global_load_dwordx4 %16, %20, off offset:256 sc0 sc1\n\t"
        "global_load_dwordx4 %17, %20, off offset:272 sc0 sc1\n\t"
        "global_load_dwordx4 %18, %20, off offset:288 sc0 sc1\n\t"
        "global_load_dwordx4 %19, %20, off offset:304 sc0 sc1\n\t"
        "s_waitcnt vmcnt(0)"
        : "=&v"(t0),"=&v"(t1),"=&v"(t2),"=&v"(t3),"=&v"(t4),"=&v"(t5),"=&v"(t6),"=&v"(t7),
          "=&v"(t8),"=&v"(t9),"=&v"(t10),"=&v"(t11),"=&v"(t12),"=&v"(t13),"=&v"(t14),"=&v"(t15),
          "=&v"(t16),"=&v"(t17),"=&v"(t18),"=&v"(t19)
        : "v"(src) : "memory");
    f32x4* d = (f32x4*)dst;
    d[0]=t0; d[1]=t1; d[2]=t2; d[3]=t3; d[4]=t4; d[5]=t5; d[6]=t6; d[7]=t7;
    d[8]=t8; d[9]=t9; d[10]=t10; d[11]=t11; d[12]=t12; d[13]=t13; d[14]=t14;
    d[15]=t15; d[16]=t16; d[17]=t17; d[18]=t18; d[19]=t19;
}

// Fence-free distributed grid barrier. Per-WG 128B-padded arrive/release
// lines; WG0 gathers/fans out. Producer ordering = vmcnt(0) before arrive.
__device__ __forceinline__ void gbar(unsigned int* arrive, unsigned int* release,
                                     int w, int tid, unsigned int k) {
    asm volatile("s_waitcnt vmcnt(0)" ::: "memory");
    __syncthreads();
    if (w == 0) {
        if (tid > 0)
            while (__hip_atomic_load(&arrive[tid * 32], __ATOMIC_RELAXED,
                                     __HIP_MEMORY_SCOPE_AGENT) < k)
                __builtin_amdgcn_s_sleep(2);
        __syncthreads();
        if (tid > 0)
            __hip_atomic_store(&release[tid * 32], k, __ATOMIC_RELAXED,
                               __HIP_MEMORY_SCOPE_AGENT);
    } else {
        if (tid == 0) {
            __hip_atomic_store(&arrive[w * 32], k, __ATOMIC_RELAXED,
                               __HIP_MEMORY_SCOPE_AGENT);
            while (__hip_atomic_load(&release[w * 32], __ATOMIC_RELAXED,
                                     __HIP_MEMORY_SCOPE_AGENT) < k)
                __builtin_amdgcn_s_sleep(2);
        }
        __syncthreads();
    }
}

// C[M,N] = A[M,K] @ B[K,N] + bias[N]   (row-major f32)
__global__ __launch_bounds__(256) void gemm_bias_kernel(
    const float* __restrict__ A, const float* __restrict__ Bm,
    const float* __restrict__ bias, float* __restrict__ C,
    int M, int N, int K)
{
    __shared__ float As[16][65];
    __shared__ float Bs[16][64];
    int tid = threadIdx.x;
    int m0 = blockIdx.y * 64, n0 = blockIdx.x * 64;
    int ar = tid >> 2, ac = (tid & 3) * 4;
    int br4 = (tid >> 6) * 4, bc = tid & 63;
    int ty = tid >> 4, tx = tid & 15;
    float acc[4][4] = {};
    for (int k0 = 0; k0 < K; k0 += 16) {
        float4 av = *(const float4*)(A + (long)(m0 + ar) * K + k0 + ac);
        As[ac + 0][ar] = av.x; As[ac + 1][ar] = av.y;
        As[ac + 2][ar] = av.z; As[ac + 3][ar] = av.w;
#pragma unroll
        for (int i = 0; i < 4; ++i)
            Bs[br4 + i][bc] = Bm[(long)(k0 + br4 + i) * N + n0 + bc];
        __syncthreads();
#pragma unroll
        for (int kk = 0; kk < 16; ++kk) {
            float a[4], b[4];
#pragma unroll
            for (int i = 0; i < 4; ++i) a[i] = As[kk][ty * 4 + i];
#pragma unroll
            for (int j = 0; j < 4; ++j) b[j] = Bs[kk][tx * 4 + j];
#pragma unroll
            for (int i = 0; i < 4; ++i)
#pragma unroll
                for (int j = 0; j < 4; ++j)
                    acc[i][j] = fmaf(a[i], b[j], acc[i][j]);
        }
        __syncthreads();
    }
#pragma unroll
    for (int i = 0; i < 4; ++i)
#pragma unroll
        for (int j = 0; j < 4; ++j)
            C[(long)(m0 + ty * 4 + i) * N + n0 + tx * 4 + j] =
                acc[i][j] + bias[n0 + tx * 4 + j];
}

__global__ void init_kernel(const float* __restrict__ EW, float* __restrict__ h,
                            float* __restrict__ c, float* __restrict__ scores,
                            unsigned int* __restrict__ arrive,
                            unsigned int* __restrict__ release)
{
    int tid = threadIdx.x;
    for (int j = tid; j < HH; j += 256) {
        float gi = EW[j], gg = EW[1280 + j], go = EW[1920 + j];
        float c1 = sigf(gi) * tanhf(gg);
        float h1 = sigf(go) * tanhf(c1);
        for (int b = 0; b < BB; ++b) { h[b * 640 + j] = h1; c[b * 640 + j] = c1; }
    }
    if (tid < 32) scores[tid] = 0.f;
    arrive[tid * 32] = 0u;
    release[tid * 32] = 0u;
}

// Dynamic LDS layout (floats):
//  Wa [16*644]   0      .. 10304     col-major [c][k] slice of [W_dec|W_hh]
//  Wo [4*644]    10304  .. 12880     col-major [c][k] slice of W_out
//  S  [32*644]   12880  .. 33488     staged h (phase A) / Tt (phase B)
//  P  [4*580]    33488  .. 35808     phase-A k-split partials
extern __shared__ float lds[];

__global__ __launch_bounds__(256, 1) void decode_kernel(
    const float* __restrict__ ENC, const float* __restrict__ EW,
    const float* __restrict__ Wdec, const float* __restrict__ Whh,
    const float* __restrict__ Wout, const float* __restrict__ bout,
    float* __restrict__ h, float* __restrict__ c,
    float* __restrict__ Tt, float* __restrict__ G,
    unsigned long long* __restrict__ pmax, float* __restrict__ psum,
    float* __restrict__ scores, float* __restrict__ out,
    unsigned int* arrive, unsigned int* release)
{
    float* Wa = lds;
    float* Wo = lds + 10304;
    float* S  = lds + 12880;
    float* P  = lds + 33488;
    __shared__ unsigned long long red_m[4];
    __shared__ float red_s[4];
    __shared__ int s_tok, s_emit;

    int w = blockIdx.x, tid = threadIdx.x;

    // ---- one-time weight staging (normal cached loads) ----
    if (w < 200) {                       // 16 cols of [W_dec|W_hh], col-major
        int cc = tid >> 4, k0 = (tid & 15) * 40;
        const float* src; long stride;
        if (w < 40) { src = Wdec + (w * 16 + cc); stride = 640; }
        else        { src = Whh + (w * 16 - 640 + cc); stride = 2560; }
        for (int i = 0; i < 40; ++i)
            Wa[cc * 644 + k0 + i] = src[(long)(k0 + i) * stride];
    }
    {                                    // 4 cols of W_out, col-major
        int cc = tid >> 6, k0 = (tid & 63) * 10;
        const float* src = Wout + (w * 4 + cc);
        for (int i = 0; i < 10; ++i)
            Wo[cc * 644 + k0 + i] = src[(long)(k0 + i) * 1024];
    }
    __syncthreads();

    int srow = tid >> 3, scol = (tid & 7) * 80;   // staging assignment
    float score = 0.f;
    unsigned int bk = 0;

    for (int t = 0; t < TT; ++t) {
        // ================= Phase A: u = h @ [W_dec|W_hh] =================
        if (w < 200) {
            stage_rows(h + srow * 640 + scol, &S[srow * 644 + scol]);
            __syncthreads();
            // 256 threads = ks(4) x bg(8) x cg(8); 2 cols x 4 batches x K/4
            int ks = tid >> 6, bg = (tid >> 3) & 7, cg = tid & 7;
            int lc = cg * 2;
            const float* wa0 = &Wa[lc * 644];
            const float* wa1 = &Wa[(lc + 1) * 644];
            const float* sp0 = &S[(4 * bg + 0) * 644];
            const float* sp1 = &S[(4 * bg + 1) * 644];
            const float* sp2 = &S[(4 * bg + 2) * 644];
            const float* sp3 = &S[(4 * bg + 3) * 644];
            float a00=0,a01=0,a10=0,a11=0,a20=0,a21=0,a30=0,a31=0;
            int kend = ks * 160 + 160;
            for (int k0 = ks * 160; k0 < kend; k0 += 4) {
                float4 w0 = *(const float4*)(wa0 + k0);
                float4 w1 = *(const float4*)(wa1 + k0);
                float4 h0 = *(const float4*)(sp0 + k0);
                float4 h1 = *(const float4*)(sp1 + k0);
                float4 h2 = *(const float4*)(sp2 + k0);
                float4 h3 = *(const float4*)(sp3 + k0);
                a00=fmaf(h0.x,w0.x,a00); a00=fmaf(h0.y,w0.y,a00); a00=fmaf(h0.z,w0.z,a00); a00=fmaf(h0.w,w0.w,a00);
                a01=fmaf(h0.x,w1.x,a01); a01=fmaf(h0.y,w1.y,a01); a01=fmaf(h0.z,w1.z,a01); a01=fmaf(h0.w,w1.w,a01);
                a10=fmaf(h1.x,w0.x,a10); a10=fmaf(h1.y,w0.y,a10); a10=fmaf(h1.z,w0.z,a10); a10=fmaf(h1.w,w0.w,a10);
                a11=fmaf(h1.x,w1.x,a11); a11=fmaf(h1.y,w1.y,a11); a11=fmaf(h1.z,w1.z,a11); a11=fmaf(h1.w,w1.w,a11);
                a20=fmaf(h2.x,w0.x,a20); a20=fmaf(h2.y,w0.y,a20); a20=fmaf(h2.z,w0.z,a20); a20=fmaf(h2.w,w0.w,a20);
                a21=fmaf(h2.x,w1.x,a21); a21=fmaf(h2.y,w1.y,a21); a21=fmaf(h2.z,w1.z,a21); a21=fmaf(h2.w,w1.w,a21);
                a30=fmaf(h3.x,w0.x,a30); a30=fmaf(h3.y,w0.y,a30); a30=fmaf(h3.z,w0.z,a30); a30=fmaf(h3.w,w0.w,a30);
                a31=fmaf(h3.x,w1.x,a31); a31=fmaf(h3.y,w1.y,a31); a31=fmaf(h3.z,w1.z,a31); a31=fmaf(h3.w,w1.w,a31);
            }
            f32x2 v;
            v.x=a00; v.y=a01; *(f32x2*)&P[ks*580 + (4*bg+0)*18 + lc] = v;
            v.x=a10; v.y=a11; *(f32x2*)&P[ks*580 + (4*bg+1)*18 + lc] = v;
            v.x=a20; v.y=a21; *(f32x2*)&P[ks*580 + (4*bg+2)*18 + lc] = v;
            v.x=a30; v.y=a31; *(f32x2*)&P[ks*580 + (4*bg+3)*18 + lc] = v;
            __syncthreads();
            // reduce 4 partials; apply ENC+tanh (dec cols) or store G
            int o0 = tid * 2, ob = o0 >> 4, oc = o0 & 15;
            float r0 = 0.f, r1 = 0.f;
#pragma unroll
            for (int kr = 0; kr < 4; ++kr) {
                f32x2 pv = *(const f32x2*)&P[kr*580 + ob*18 + oc];
                r0 += pv.x; r1 += pv.y;
            }
            int gc = w * 16 + oc;
            if (gc < 640) {
                float2 ev = *(const float2*)&ENC[((long)ob * TT + t) * 640 + gc];
                f32x2 tv; tv.x = tanhf(ev.x + r0); tv.y = tanhf(ev.y + r1);
                stg2_sc(&Tt[ob * 640 + gc], tv);
            } else {
                f32x2 gv; gv.x = r0; gv.y = r1;
                stg2_sc(&G[ob * 2560 + gc - 640], gv);
            }
        }
        gbar(arrive, release, w, tid, ++bk);

        // ================= Phase B: logits + per-WG argmax/sumexp =========
        stage_rows(Tt + srow * 640 + scol, &S[srow * 644 + scol]);
        __syncthreads();
        {
            int half = tid & 1, p2 = tid >> 1, bb = p2 >> 2, cl = p2 & 3;
            const float* tb = &S[bb * 644 + half * 320];
            const float* wb = &Wo[cl * 644 + half * 320];
            float acc = 0.f;
            for (int k0 = 0; k0 < 320; k0 += 4) {
                float4 tv = *(const float4*)(tb + k0);
                float4 wv = *(const float4*)(wb + k0);
                acc = fmaf(tv.x, wv.x, acc);
                acc = fmaf(tv.y, wv.y, acc);
                acc = fmaf(tv.z, wv.z, acc);
                acc = fmaf(tv.w, wv.w, acc);
            }
            float oth = __shfl_xor(acc, 1);
            int col = w * 4 + cl;
            float logit = acc + oth + bout[col];
            float sexp = expf(logit);
            unsigned long long pk =
                ((unsigned long long)fkey(logit) << 32) | (unsigned int)(1023 - col);
            unsigned long long o;
            o = shflxor_u64(pk, 2); if (o > pk) pk = o; sexp += __shfl_xor(sexp, 2);
            o = shflxor_u64(pk, 4); if (o > pk) pk = o; sexp += __shfl_xor(sexp, 4);
            if ((tid & 7) == 0) {
                stg2u_sc(pmax + bb * 256 + w, pk);
                stg1_sc(psum + bb * 256 + w, sexp);
            }
        }
        gbar(arrive, release, w, tid, ++bk);

        // ================= Phase C: reduce, emit, LSTM update =============
        if (w < 32) {
            int b = w;
            u32x2 mv; float s;
            asm volatile(
                "global_load_dwordx2 %0, %2, off sc0 sc1\n\t"
                "global_load_dword   %1, %3, off sc0 sc1\n\t"
                "s_waitcnt vmcnt(0)"
                : "=&v"(mv), "=&v"(s)
                : "v"(pmax + b * 256 + tid), "v"(psum + b * 256 + tid)
                : "memory");
            unsigned long long m = ((unsigned long long)mv.y << 32) | mv.x;
#pragma unroll
            for (int mask = 1; mask <= 32; mask <<= 1) {
                unsigned long long o = shflxor_u64(m, mask);
                if (o > m) m = o;
                s += __shfl_xor(s, mask);
            }
            if ((tid & 63) == 0) { red_m[tid >> 6] = m; red_s[tid >> 6] = s; }
            __syncthreads();
            if (tid == 0) {
                unsigned long long mm = red_m[0];
                float ss = red_s[0];
#pragma unroll
                for (int i = 1; i < 4; ++i) {
                    if (red_m[i] > mm) mm = red_m[i];
                    ss += red_s[i];
                }
                int tok = 1023 - (int)(mm & 0xFFFFFFFFu);
                unsigned int key = (unsigned int)(mm >> 32);
                unsigned int u = (key & 0x80000000u) ? (key ^ 0x80000000u) : ~key;
                float maxlogit = __uint_as_float(u);
                int emit = (tok != 0);
                out[b * TT + t] = (float)tok;
                if (emit) score += maxlogit - logf(ss);
                s_tok = tok; s_emit = emit;
            }
            __syncthreads();
            if (s_emit && tid < 160) {
                int j4 = tid * 4;
                const float* gb = G + b * 2560 + j4;
                f32x4 vi, vf, vg, vo;
                asm volatile(
                    "global_load_dwordx4 %0, %4, off sc0 sc1\n\t"
                    "global_load_dwordx4 %1, %5, off sc0 sc1\n\t"
                    "global_load_dwordx4 %2, %6, off sc0 sc1\n\t"
                    "global_load_dwordx4 %3, %7, off sc0 sc1\n\t"
                    "s_waitcnt vmcnt(0)"
                    : "=&v"(vi), "=&v"(vf), "=&v"(vg), "=&v"(vo)
                    : "v"(gb), "v"(gb + 640), "v"(gb + 1280), "v"(gb + 1920)
                    : "memory");
                const float* ew = EW + (long)s_tok * 2560 + j4;
                float4 ei = *(const float4*)(ew);
                float4 ef = *(const float4*)(ew + 640);
                float4 eg = *(const float4*)(ew + 1280);
                float4 eo = *(const float4*)(ew + 1920);
                float4 cv = *(const float4*)(c + b * 640 + j4);
                float4 cn; f32x4 hn;
                cn.x = sigf(vf.x + ef.x) * cv.x + sigf(vi.x + ei.x) * tanhf(vg.x + eg.x);
                cn.y = sigf(vf.y + ef.y) * cv.y + sigf(vi.y + ei.y) * tanhf(vg.y + eg.y);
                cn.z = sigf(vf.z + ef.z) * cv.z + sigf(vi.z + ei.z) * tanhf(vg.z + eg.z);
                cn.w = sigf(vf.w + ef.w) * cv.w + sigf(vi.w + ei.w) * tanhf(vg.w + eg.w);
                hn.x = sigf(vo.x + eo.x) * tanhf(cn.x);
                hn.y = sigf(vo.y + eo.y) * tanhf(cn.y);
                hn.z = sigf(vo.z + eo.z) * tanhf(cn.z);
                hn.w = sigf(vo.w + eo.w) * tanhf(cn.w);
                *(float4*)(c + b * 640 + j4) = cn;        // normal (same-WG reuse)
                stg4_sc(h + b * 640 + j4, hn);            // coherent for phase A
            }
        }
        gbar(arrive, release, w, tid, ++bk);
    }

    if (w < 32 && tid == 0)
        stg1_sc(scores + w, score);
    gbar(arrive, release, w, tid, ++bk);

    if (w == 0 && tid == 0) {
        f32x4 s0,s1,s2,s3,s4,s5,s6,s7;
        asm volatile(
            "global_load_dwordx4 %0, %8, off sc0 sc1\n\t"
            "global_load_dwordx4 %1, %8, off offset:16 sc0 sc1\n\t"
            "global_load_dwordx4 %2, %8, off offset:32 sc0 sc1\n\t"
            "global_load_dwordx4 %3, %8, off offset:48 sc0 sc1\n\t"
            "global_load_dwordx4 %4, %8, off offset:64 sc0 sc1\n\t"
            "global_load_dwordx4 %5, %8, off offset:80 sc0 sc1\n\t"
            "global_load_dwordx4 %6, %8, off offset:96 sc0 sc1\n\t"
            "global_load_dwordx4 %7, %8, off offset:112 sc0 sc1\n\t"
            "s_waitcnt vmcnt(0)"
            : "=&v"(s0),"=&v"(s1),"=&v"(s2),"=&v"(s3),
              "=&v"(s4),"=&v"(s5),"=&v"(s6),"=&v"(s7)
            : "v"(scores) : "memory");
        float sum = expf(s0.x)+expf(s0.y)+expf(s0.z)+expf(s0.w)
                  + expf(s1.x)+expf(s1.y)+expf(s1.z)+expf(s1.w)
                  + expf(s2.x)+expf(s2.y)+expf(s2.z)+expf(s2.w)
                  + expf(s3.x)+expf(s3.y)+expf(s3.z)+expf(s3.w)
                  + expf(s4.x)+expf(s4.y)+expf(s4.z)+expf(s4.w)
                  + expf(s5.x)+expf(s5.y)+expf(s5.z)+expf(s5.w)
                  + expf(s6.x)+expf(s6.y)+expf(s6.z)+expf(s6.w)
                  + expf(s7.x)+expf(s7.y)+expf(s7.z)+expf(s7.w);
        out[16000] = sum / 32.0f;
    }
}

extern "C" void kernel_launch(void* const* d_in, const int* in_sizes, int n_in,
                              void* d_out, int out_size, void* d_ws, size_t ws_size,
                              hipStream_t stream)
{
    const float* X     = (const float*)d_in[0];
    const float* E     = (const float*)d_in[1];
    const float* W_ih  = (const float*)d_in[2];
    const float* W_hh  = (const float*)d_in[3];
    const float* b_l   = (const float*)d_in[4];
    const float* W_enc = (const float*)d_in[5];
    const float* W_dec = (const float*)d_in[6];
    const float* b_j   = (const float*)d_in[7];
    const float* W_out = (const float*)d_in[8];
    const float* b_out = (const float*)d_in[9];

    float* ws  = (float*)d_ws;
    float* ENC = ws;
    float* EW  = ws + 10240000;
    float* h   = ws + 12861440;
    float* c   = ws + 12881920;
    float* Tt  = ws + 12902400;
    float* G   = ws + 12922880;
    unsigned long long* pmax = (unsigned long long*)(ws + 13004800);
    float* psum   = ws + 13021184;
    float* scores = ws + 13029376;
    unsigned int* arrive  = (unsigned int*)(ws + 13029440);
    unsigned int* release = (unsigned int*)(ws + 13037632);
    float* out = (float*)d_out;

    gemm_bias_kernel<<<dim3(10, 250), 256, 0, stream>>>(X, W_enc, b_j, ENC, 16000, 640, 640);
    gemm_bias_kernel<<<dim3(40, 16), 256, 0, stream>>>(E, W_ih, b_l, EW, 1024, 2560, 640);
    init_kernel<<<1, 256, 0, stream>>>(EW, h, c, scores, arrive, release);

    void* args[] = {
        (void*)&ENC, (void*)&EW, (void*)&W_dec, (void*)&W_hh,
        (void*)&W_out, (void*)&b_out, (void*)&h, (void*)&c,
        (void*)&Tt, (void*)&G, (void*)&pmax, (void*)&psum,
        (void*)&scores, (void*)&out, (void*)&arrive, (void*)&release
    };
    hipLaunchCooperativeKernel((const void*)decode_kernel, dim3(NWG), dim3(256),
                               args, 143232, stream);
}

// Round 7
// 26303.134 us; speedup vs baseline: 1.2252x; 1.2252x over previous
//
#include <hip/hip_runtime.h>
#include <math.h>

#define BB 32
#define TT 500
#define HH 640
#define VV 1024
#define NWG 100

typedef float f32x4 __attribute__((ext_vector_type(4)));
typedef float f32x2 __attribute__((ext_vector_type(2)));
typedef unsigned int u32x2 __attribute__((ext_vector_type(2)));

// ws layout (float offsets)
//  ENC    : 0           (16000*640 = 10,240,000)
//  EW     : 10,240,000  (1024*2560 = 2,621,440)
//  h      : 12,861,440  (32*640)
//  c      : 12,881,920  (32*640)
//  Tt     : 12,902,400  (32*640)
//  G      : 12,922,880  (32*2560 -> 13,004,800)
//  pmax   : 13,004,800  (32*128 u64 = 8,192 floats -> 13,012,992)
//  psum   : 13,012,992  (32*128 = 4,096 -> 13,017,088)
//  scores : 13,017,088  (64 -> 13,017,152)
//  arrive : 13,017,152  (100*32 u32 = 3,200 -> 13,020,352)
//  release: 13,020,352  (3,200 -> 13,023,552)
//  WcatT  : 13,023,552  (3200*640 = 2,048,000 -> 15,071,552)   [W_dec|W_hh]^T
//  WoT    : 15,071,552  (1024*640 = 655,360 -> 15,726,912)     W_out^T
// total 15,726,912 floats = 62.9 MB

__device__ __forceinline__ float sigf(float x) { return 1.0f / (1.0f + expf(-x)); }

__device__ __forceinline__ unsigned int fkey(float x) {
    unsigned int u = __float_as_uint(x);
    return (u & 0x80000000u) ? ~u : (u | 0x80000000u);
}

__device__ __forceinline__ unsigned long long shflxor_u64(unsigned long long v, int m) {
    unsigned int lo = (unsigned int)v, hi = (unsigned int)(v >> 32);
    lo = (unsigned int)__shfl_xor((int)lo, m);
    hi = (unsigned int)__shfl_xor((int)hi, m);
    return ((unsigned long long)hi << 32) | lo;
}

// ---- coherent (IC-level) stores: bypass L1/L2, no fences needed ----
__device__ __forceinline__ void stg1_sc(float* p, float v) {
    asm volatile("global_store_dword %0, %1, off sc0 sc1" :: "v"(p), "v"(v) : "memory");
}
__device__ __forceinline__ void stg4_sc(float* p, f32x4 v) {
    asm volatile("global_store_dwordx4 %0, %1, off sc0 sc1" :: "v"(p), "v"(v) : "memory");
}
__device__ __forceinline__ void stg2u_sc(unsigned long long* p, unsigned long long v) {
    u32x2 uv; uv.x = (unsigned int)v; uv.y = (unsigned int)(v >> 32);
    asm volatile("global_store_dwordx2 %0, %1, off sc0 sc1" :: "v"(p), "v"(uv) : "memory");
}

// Stage 80 contiguous floats (coherent IC loads) into LDS. Single asm block.
__device__ __forceinline__ void stage_rows(const float* src, float* dst) {
    f32x4 t0,t1,t2,t3,t4,t5,t6,t7,t8,t9,t10,t11,t12,t13,t14,t15,t16,t17,t18,t19;
    asm volatile(
        "global_load_dwordx4 %0,  %20, off sc0 sc1\n\t"
        "global_load_dwordx4 %1,  %20, off offset:16 sc0 sc1\n\t"
        "global_load_dwordx4 %2,  %20, off offset:32 sc0 sc1\n\t"
        "global_load_dwordx4 %3,  %20, off offset:48 sc0 sc1\n\t"
        "global_load_dwordx4 %4,  %20, off offset:64 sc0 sc1\n\t"
        "global_load_dwordx4 %5,  %20, off offset:80 sc0 sc1\n\t"
        "global_load_dwordx4 %6,  %20, off offset:96 sc0 sc1\n\t"
        "global_load_dwordx4 %7,  %20, off offset:112 sc0 sc1\n\t"
        "global_load_dwordx4 %8,  %20, off offset:128 sc0 sc1\n\t"
        "global_load_dwordx4 %9,  %20, off offset:144 sc0 sc1\n\t"
        "global_load_dwordx4 %10, %20, off offset:160 sc0 sc1\n\t"
        "global_load_dwordx4 %11, %20, off offset:176 sc0 sc1\n\t"
        "global_load_dwordx4 %12, %20, off offset:192 sc0 sc1\n\t"
        "global_load_dwordx4 %13, %20, off offset:208 sc0 sc1\n\t"
        "global_load_dwordx4 %14, %20, off offset:224 sc0 sc1\n\t"
        "global_load_dwordx4 %15, %20, off offset:240 sc0 sc1\n\t"
        "global_load_dwordx4 %16, %20, off offset:256 sc0 sc1\n\t"
        "global_load_dwordx4 %17, %20, off offset:272 sc0 sc1\n\t"
        "global_load_dwordx4 %18, %20, off offset:288 sc0 sc1\n\t"
        "global_load_dwordx4 %19, %20, off offset:304 sc0 sc1\n\t"
        "s_waitcnt vmcnt(0)"
        : "=&v"(t0),"=&v"(t1),"=&v"(t2),"=&v"(t3),"=&v"(t4),"=&v"(t5),"=&v"(t6),"=&v"(t7),
          "=&v"(t8),"=&v"(t9),"=&v"(t10),"=&v"(t11),"=&v"(t12),"=&v"(t13),"=&v"(t14),"=&v"(t15),
          "=&v"(t16),"=&v"(t17),"=&v"(t18),"=&v"(t19)
        : "v"(src) : "memory");
    f32x4* d = (f32x4*)dst;
    d[0]=t0; d[1]=t1; d[2]=t2; d[3]=t3; d[4]=t4; d[5]=t5; d[6]=t6; d[7]=t7;
    d[8]=t8; d[9]=t9; d[10]=t10; d[11]=t11; d[12]=t12; d[13]=t13; d[14]=t14;
    d[15]=t15; d[16]=t16; d[17]=t17; d[18]=t18; d[19]=t19;
}

// Fence-free distributed grid barrier (validated R5). Per-WG 128B-padded slots.
__device__ __forceinline__ void gbar(unsigned int* arrive, unsigned int* release,
                                     int w, int tid, unsigned int k) {
    asm volatile("s_waitcnt vmcnt(0)" ::: "memory");
    __syncthreads();
    if (w == 0) {
        if (tid > 0 && tid < NWG)
            while (__hip_atomic_load(&arrive[tid * 32], __ATOMIC_RELAXED,
                                     __HIP_MEMORY_SCOPE_AGENT) < k)
                __builtin_amdgcn_s_sleep(2);
        __syncthreads();
        if (tid > 0 && tid < NWG)
            __hip_atomic_store(&release[tid * 32], k, __ATOMIC_RELAXED,
                               __HIP_MEMORY_SCOPE_AGENT);
    } else {
        if (tid == 0) {
            __hip_atomic_store(&arrive[w * 32], k, __ATOMIC_RELAXED,
                               __HIP_MEMORY_SCOPE_AGENT);
            while (__hip_atomic_load(&release[w * 32], __ATOMIC_RELAXED,
                                     __HIP_MEMORY_SCOPE_AGENT) < k)
                __builtin_amdgcn_s_sleep(2);
        }
        __syncthreads();
    }
}

// C[M,N] = A[M,K] @ B[K,N] + bias[N]   (row-major f32)
__global__ __launch_bounds__(256) void gemm_bias_kernel(
    const float* __restrict__ A, const float* __restrict__ Bm,
    const float* __restrict__ bias, float* __restrict__ C,
    int M, int N, int K)
{
    __shared__ float As[16][65];
    __shared__ float Bs[16][64];
    int tid = threadIdx.x;
    int m0 = blockIdx.y * 64, n0 = blockIdx.x * 64;
    int ar = tid >> 2, ac = (tid & 3) * 4;
    int br4 = (tid >> 6) * 4, bc = tid & 63;
    int ty = tid >> 4, tx = tid & 15;
    float acc[4][4] = {};
    for (int k0 = 0; k0 < K; k0 += 16) {
        float4 av = *(const float4*)(A + (long)(m0 + ar) * K + k0 + ac);
        As[ac + 0][ar] = av.x; As[ac + 1][ar] = av.y;
        As[ac + 2][ar] = av.z; As[ac + 3][ar] = av.w;
#pragma unroll
        for (int i = 0; i < 4; ++i)
            Bs[br4 + i][bc] = Bm[(long)(k0 + br4 + i) * N + n0 + bc];
        __syncthreads();
#pragma unroll
        for (int kk = 0; kk < 16; ++kk) {
            float a[4], b[4];
#pragma unroll
            for (int i = 0; i < 4; ++i) a[i] = As[kk][ty * 4 + i];
#pragma unroll
            for (int j = 0; j < 4; ++j) b[j] = Bs[kk][tx * 4 + j];
#pragma unroll
            for (int i = 0; i < 4; ++i)
#pragma unroll
                for (int j = 0; j < 4; ++j)
                    acc[i][j] = fmaf(a[i], b[j], acc[i][j]);
        }
        __syncthreads();
    }
#pragma unroll
    for (int i = 0; i < 4; ++i)
#pragma unroll
        for (int j = 0; j < 4; ++j)
            C[(long)(m0 + ty * 4 + i) * N + n0 + tx * 4 + j] =
                acc[i][j] + bias[n0 + tx * 4 + j];
}

// WcatT[c][k] = c<640 ? Wdec[k][c] : Whh[k][c-640]
__global__ void transpose_cat_kernel(const float* __restrict__ Wdec,
                                     const float* __restrict__ Whh,
                                     float* __restrict__ WcatT)
{
    int c = blockIdx.x;
    const float* src; long stride;
    if (c < 640) { src = Wdec + c; stride = 640; }
    else         { src = Whh + (c - 640); stride = 2560; }
    for (int k = threadIdx.x; k < 640; k += 256)
        WcatT[(long)c * 640 + k] = src[(long)k * stride];
}

// WoT[v][k] = Wout[k][v]
__global__ void transpose_out_kernel(const float* __restrict__ Wout,
                                     float* __restrict__ WoT)
{
    int v = blockIdx.x;
    for (int k = threadIdx.x; k < 640; k += 256)
        WoT[(long)v * 640 + k] = Wout[(long)k * 1024 + v];
}

__global__ void init_kernel(const float* __restrict__ EW, float* __restrict__ h,
                            float* __restrict__ c, float* __restrict__ scores,
                            unsigned int* __restrict__ arrive,
                            unsigned int* __restrict__ release,
                            unsigned long long* __restrict__ pmax,
                            float* __restrict__ psum)
{
    int tid = threadIdx.x;
    for (int j = tid; j < HH; j += 256) {
        float gi = EW[j], gg = EW[1280 + j], go = EW[1920 + j];
        float c1 = sigf(gi) * tanhf(gg);
        float h1 = sigf(go) * tanhf(c1);
        for (int b = 0; b < BB; ++b) { h[b * 640 + j] = h1; c[b * 640 + j] = c1; }
    }
    if (tid < 32) scores[tid] = 0.f;
    if (tid < NWG) { arrive[tid * 32] = 0u; release[tid * 32] = 0u; }
    for (int i = tid; i < 32 * 128; i += 256) { pmax[i] = 0ull; psum[i] = 0.f; }
}

// Dynamic LDS (floats):
//  S [32][644]  0     .. 20608   staged h (A) / Tt (B)
//  P [8][32][36] 20608 .. 29824  phase-A split-K partials
extern __shared__ float lds[];

__global__ __launch_bounds__(256, 1) void decode_kernel(
    const float* __restrict__ ENC, const float* __restrict__ EW,
    const float* __restrict__ WcatT, const float* __restrict__ WoT,
    const float* __restrict__ bout,
    float* __restrict__ h, float* __restrict__ c,
    float* __restrict__ Tt, float* __restrict__ G,
    unsigned long long* __restrict__ pmax, float* __restrict__ psum,
    float* __restrict__ scores, float* __restrict__ out,
    unsigned int* arrive, unsigned int* release)
{
    float* S = lds;
    float* P = lds + 20608;
    __shared__ int s_tok, s_emit;

    int w = blockIdx.x, tid = threadIdx.x;

    // staging assignment (rotated per WG to de-hot-line the fabric)
    int srow = ((tid >> 3) + w) & 31;
    int scol = (tid & 7) * 80;
    int sgl  = srow * 640 + scol;    // global offset within h/Tt
    int sll  = srow * 644 + scol;    // LDS offset

    // phase-A decomposition: 32 cols/WG; thread = (ks 8) x (bg 8 -> 4 b) x (cg 4 -> 8 cols)
    int ks = tid >> 5, bg = (tid >> 2) & 7, cg = tid & 3;
    int b0 = bg * 4, c0 = cg * 8;
    int C0 = w * 32;
    const float* wbase = WcatT + ((long)(C0 + c0)) * 640 + ks * 80;

    // phase-B decomposition: thread = (b 32) x (k-slice 8 of 80)
    int pb = tid >> 3, pk8 = (tid & 7) * 80;
    int V0 = w * 10 + (w < 24 ? w : 24);
    int nv = 10 + (w < 24 ? 1 : 0);

    float score = 0.f;
    unsigned int bk = 0;

    for (int t = 0; t < TT; ++t) {
        // ============ Phase A: u = h @ [W_dec|W_hh]; Tt / G ============
        stage_rows(h + sgl, &S[sll]);
        __syncthreads();
        {
            const float* sb = &S[b0 * 644 + ks * 80];
            float acc[4][8] = {};
            for (int kk = 0; kk < 80; kk += 4) {
                float4 hv[4];
#pragma unroll
                for (int i = 0; i < 4; ++i)
                    hv[i] = *(const float4*)(sb + i * 644 + kk);
#pragma unroll
                for (int j = 0; j < 8; ++j) {
                    float4 wv = *(const float4*)(wbase + (long)j * 640 + kk);
#pragma unroll
                    for (int i = 0; i < 4; ++i) {
                        acc[i][j] = fmaf(hv[i].x, wv.x, acc[i][j]);
                        acc[i][j] = fmaf(hv[i].y, wv.y, acc[i][j]);
                        acc[i][j] = fmaf(hv[i].z, wv.z, acc[i][j]);
                        acc[i][j] = fmaf(hv[i].w, wv.w, acc[i][j]);
                    }
                }
            }
#pragma unroll
            for (int i = 0; i < 4; ++i) {
                float4 v0, v1;
                v0.x = acc[i][0]; v0.y = acc[i][1]; v0.z = acc[i][2]; v0.w = acc[i][3];
                v1.x = acc[i][4]; v1.y = acc[i][5]; v1.z = acc[i][6]; v1.w = acc[i][7];
                *(float4*)&P[ks * 1152 + (b0 + i) * 36 + c0]     = v0;
                *(float4*)&P[ks * 1152 + (b0 + i) * 36 + c0 + 4] = v1;
            }
        }
        __syncthreads();
        {
            int rb = tid >> 3, rc = (tid & 7) * 4;
            float r0 = 0.f, r1 = 0.f, r2 = 0.f, r3 = 0.f;
#pragma unroll
            for (int kr = 0; kr < 8; ++kr) {
                float4 pv = *(const float4*)&P[kr * 1152 + rb * 36 + rc];
                r0 += pv.x; r1 += pv.y; r2 += pv.z; r3 += pv.w;
            }
            int gc = C0 + rc;
            f32x4 ov;
            if (w < 20) {
                float4 ev = *(const float4*)&ENC[((long)rb * TT + t) * 640 + gc];
                ov.x = tanhf(ev.x + r0); ov.y = tanhf(ev.y + r1);
                ov.z = tanhf(ev.z + r2); ov.w = tanhf(ev.w + r3);
                stg4_sc(&Tt[rb * 640 + gc], ov);
            } else {
                ov.x = r0; ov.y = r1; ov.z = r2; ov.w = r3;
                stg4_sc(&G[rb * 2560 + gc - 640], ov);
            }
        }
        gbar(arrive, release, w, tid, ++bk);

        // ============ Phase B: logits + per-WG argmax/sumexp ============
        stage_rows(Tt + sgl, &S[sll]);
        __syncthreads();
        {
            const float* tb = &S[pb * 644 + pk8];
            unsigned long long best = 0ull; float sex = 0.f;
            for (int vi = 0; vi < nv; ++vi) {
                int v = V0 + vi;
                const float* wb = WoT + (long)v * 640 + pk8;
                float acc = 0.f;
                for (int kk = 0; kk < 80; kk += 4) {
                    float4 tv = *(const float4*)(tb + kk);
                    float4 wv = *(const float4*)(wb + kk);
                    acc = fmaf(tv.x, wv.x, acc);
                    acc = fmaf(tv.y, wv.y, acc);
                    acc = fmaf(tv.z, wv.z, acc);
                    acc = fmaf(tv.w, wv.w, acc);
                }
                acc += __shfl_xor(acc, 1);
                acc += __shfl_xor(acc, 2);
                acc += __shfl_xor(acc, 4);
                if ((tid & 7) == 0) {
                    float logit = acc + bout[v];
                    sex += expf(logit);
                    unsigned long long q =
                        ((unsigned long long)fkey(logit) << 32) | (unsigned int)(1023 - v);
                    if (q > best) best = q;
                }
            }
            if ((tid & 7) == 0) {
                stg2u_sc(pmax + pb * 128 + w, best);
                stg1_sc(psum + pb * 128 + w, sex);
            }
        }
        gbar(arrive, release, w, tid, ++bk);

        // ============ Phase C: reduce, emit, LSTM update ============
        if (w < 32) {
            int b = w;
            if (tid < 64) {
                u32x2 m1, m2; float s1, s2;
                asm volatile(
                    "global_load_dwordx2 %0, %4, off sc0 sc1\n\t"
                    "global_load_dwordx2 %1, %5, off sc0 sc1\n\t"
                    "global_load_dword   %2, %6, off sc0 sc1\n\t"
                    "global_load_dword   %3, %7, off sc0 sc1\n\t"
                    "s_waitcnt vmcnt(0)"
                    : "=&v"(m1), "=&v"(m2), "=&v"(s1), "=&v"(s2)
                    : "v"(pmax + b * 128 + tid), "v"(pmax + b * 128 + 64 + tid),
                      "v"(psum + b * 128 + tid), "v"(psum + b * 128 + 64 + tid)
                    : "memory");
                unsigned long long ma = ((unsigned long long)m1.y << 32) | m1.x;
                unsigned long long mb = ((unsigned long long)m2.y << 32) | m2.x;
                if (mb > ma) ma = mb;
                float s = s1 + s2;
#pragma unroll
                for (int mask = 1; mask <= 32; mask <<= 1) {
                    unsigned long long o = shflxor_u64(ma, mask);
                    if (o > ma) ma = o;
                    s += __shfl_xor(s, mask);
                }
                if (tid == 0) {
                    int tok = 1023 - (int)(ma & 0xFFFFFFFFu);
                    unsigned int key = (unsigned int)(ma >> 32);
                    unsigned int u = (key & 0x80000000u) ? (key ^ 0x80000000u) : ~key;
                    float maxlogit = __uint_as_float(u);
                    int emit = (tok != 0);
                    out[b * TT + t] = (float)tok;
                    if (emit) score += maxlogit - logf(s);
                    s_tok = tok; s_emit = emit;
                }
            }
            __syncthreads();
            if (s_emit && tid < 160) {
                int j4 = tid * 4;
                const float* gb = G + b * 2560 + j4;
                f32x4 vi, vf, vg, vo;
                asm volatile(
                    "global_load_dwordx4 %0, %4, off sc0 sc1\n\t"
                    "global_load_dwordx4 %1, %5, off sc0 sc1\n\t"
                    "global_load_dwordx4 %2, %6, off sc0 sc1\n\t"
                    "global_load_dwordx4 %3, %7, off sc0 sc1\n\t"
                    "s_waitcnt vmcnt(0)"
                    : "=&v"(vi), "=&v"(vf), "=&v"(vg), "=&v"(vo)
                    : "v"(gb), "v"(gb + 640), "v"(gb + 1280), "v"(gb + 1920)
                    : "memory");
                const float* ew = EW + (long)s_tok * 2560 + j4;
                float4 ei = *(const float4*)(ew);
                float4 ef = *(const float4*)(ew + 640);
                float4 eg = *(const float4*)(ew + 1280);
                float4 eo = *(const float4*)(ew + 1920);
                float4 cv = *(const float4*)(c + b * 640 + j4);
                float4 cn; f32x4 hn;
                cn.x = sigf(vf.x + ef.x) * cv.x + sigf(vi.x + ei.x) * tanhf(vg.x + eg.x);
                cn.y = sigf(vf.y + ef.y) * cv.y + sigf(vi.y + ei.y) * tanhf(vg.y + eg.y);
                cn.z = sigf(vf.z + ef.z) * cv.z + sigf(vi.z + ei.z) * tanhf(vg.z + eg.z);
                cn.w = sigf(vf.w + ef.w) * cv.w + sigf(vi.w + ei.w) * tanhf(vg.w + eg.w);
                hn.x = sigf(vo.x + eo.x) * tanhf(cn.x);
                hn.y = sigf(vo.y + eo.y) * tanhf(cn.y);
                hn.z = sigf(vo.z + eo.z) * tanhf(cn.z);
                hn.w = sigf(vo.w + eo.w) * tanhf(cn.w);
                *(float4*)(c + b * 640 + j4) = cn;   // plain: same-WG reuse only
                stg4_sc(h + b * 640 + j4, hn);       // coherent for next phase A
            }
        }
        gbar(arrive, release, w, tid, ++bk);
    }

    if (w < 32 && tid == 0)
        stg1_sc(scores + w, score);
    gbar(arrive, release, w, tid, ++bk);

    if (w == 0 && tid == 0) {
        f32x4 s0,s1,s2,s3,s4,s5,s6,s7;
        asm volatile(
            "global_load_dwordx4 %0, %8, off sc0 sc1\n\t"
            "global_load_dwordx4 %1, %8, off offset:16 sc0 sc1\n\t"
            "global_load_dwordx4 %2, %8, off offset:32 sc0 sc1\n\t"
            "global_load_dwordx4 %3, %8, off offset:48 sc0 sc1\n\t"
            "global_load_dwordx4 %4, %8, off offset:64 sc0 sc1\n\t"
            "global_load_dwordx4 %5, %8, off offset:80 sc0 sc1\n\t"
            "global_load_dwordx4 %6, %8, off offset:96 sc0 sc1\n\t"
            "global_load_dwordx4 %7, %8, off offset:112 sc0 sc1\n\t"
            "s_waitcnt vmcnt(0)"
            : "=&v"(s0),"=&v"(s1),"=&v"(s2),"=&v"(s3),
              "=&v"(s4),"=&v"(s5),"=&v"(s6),"=&v"(s7)
            : "v"(scores) : "memory");
        float sum = expf(s0.x)+expf(s0.y)+expf(s0.z)+expf(s0.w)
                  + expf(s1.x)+expf(s1.y)+expf(s1.z)+expf(s1.w)
                  + expf(s2.x)+expf(s2.y)+expf(s2.z)+expf(s2.w)
                  + expf(s3.x)+expf(s3.y)+expf(s3.z)+expf(s3.w)
                  + expf(s4.x)+expf(s4.y)+expf(s4.z)+expf(s4.w)
                  + expf(s5.x)+expf(s5.y)+expf(s5.z)+expf(s5.w)
                  + expf(s6.x)+expf(s6.y)+expf(s6.z)+expf(s6.w)
                  + expf(s7.x)+expf(s7.y)+expf(s7.z)+expf(s7.w);
        out[16000] = sum / 32.0f;
    }
}

extern "C" void kernel_launch(void* const* d_in, const int* in_sizes, int n_in,
                              void* d_out, int out_size, void* d_ws, size_t ws_size,
                              hipStream_t stream)
{
    const float* X     = (const float*)d_in[0];
    const float* E     = (const float*)d_in[1];
    const float* W_ih  = (const float*)d_in[2];
    const float* W_hh  = (const float*)d_in[3];
    const float* b_l   = (const float*)d_in[4];
    const float* W_enc = (const float*)d_in[5];
    const float* W_dec = (const float*)d_in[6];
    const float* b_j   = (const float*)d_in[7];
    const float* W_out = (const float*)d_in[8];
    const float* b_out = (const float*)d_in[9];

    float* ws  = (float*)d_ws;
    float* ENC = ws;
    float* EW  = ws + 10240000;
    float* h   = ws + 12861440;
    float* c   = ws + 12881920;
    float* Tt  = ws + 12902400;
    float* G   = ws + 12922880;
    unsigned long long* pmax = (unsigned long long*)(ws + 13004800);
    float* psum   = ws + 13012992;
    float* scores = ws + 13017088;
    unsigned int* arrive  = (unsigned int*)(ws + 13017152);
    unsigned int* release = (unsigned int*)(ws + 13020352);
    float* WcatT  = ws + 13023552;
    float* WoT    = ws + 15071552;
    float* out = (float*)d_out;

    gemm_bias_kernel<<<dim3(10, 250), 256, 0, stream>>>(X, W_enc, b_j, ENC, 16000, 640, 640);
    gemm_bias_kernel<<<dim3(40, 16), 256, 0, stream>>>(E, W_ih, b_l, EW, 1024, 2560, 640);
    transpose_cat_kernel<<<3200, 256, 0, stream>>>(W_dec, W_hh, WcatT);
    transpose_out_kernel<<<1024, 256, 0, stream>>>(W_out, WoT);
    init_kernel<<<1, 256, 0, stream>>>(EW, h, c, scores, arrive, release, pmax, psum);

    void* args[] = {
        (void*)&ENC, (void*)&EW, (void*)&WcatT, (void*)&WoT,
        (void*)&b_out, (void*)&h, (void*)&c, (void*)&Tt, (void*)&G,
        (void*)&pmax, (void*)&psum, (void*)&scores, (void*)&out,
        (void*)&arrive, (void*)&release
    };
    hipLaunchCooperativeKernel((const void*)decode_kernel, dim3(NWG), dim3(256),
                               args, 119296, stream);
}